// Round 1
// baseline (3121.372 us; speedup 1.0000x reference)
//
#include <hip/hip_runtime.h>
#include <stdint.h>

// ============================================================================
// R1: bf16 MFMA GEMMs (m97 structure + xor LDS swizzle) + fp32 flash attention
// Shapes fixed by the problem: B=2, S=2048, D=2048, H=16, HD=128.
// ws layout (bytes): xb@0(16M) wq@16M wk@24M wv@32M wo@40M q@48M k@64M v@80M
//                    attn_out@96M  -> total 112 MB (requires ws_size >= that).
// ============================================================================

typedef __attribute__((ext_vector_type(8))) short short8;
typedef __attribute__((ext_vector_type(4))) float f32x4;

#define DEV static __device__ __forceinline__

DEV unsigned short f2bf(float f) {
  unsigned u = __builtin_bit_cast(unsigned, f);
  u += 0x7fffu + ((u >> 16) & 1u);           // RNE
  return (unsigned short)(u >> 16);
}
DEV float bflo(unsigned u) { return __builtin_bit_cast(float, u << 16); }
DEV float bfhi(unsigned u) { return __builtin_bit_cast(float, u & 0xffff0000u); }

DEV void unpack8(uint4 u, float* f) {
  f[0] = bflo(u.x); f[1] = bfhi(u.x);
  f[2] = bflo(u.y); f[3] = bfhi(u.y);
  f[4] = bflo(u.z); f[5] = bfhi(u.z);
  f[6] = bflo(u.w); f[7] = bfhi(u.w);
}

// async global->LDS, 16B per lane; LDS dest must be wave-uniform base (+lane*16)
DEV void async16(const void* g, void* l) {
  __builtin_amdgcn_global_load_lds(
      (const __attribute__((address_space(1))) unsigned int*)g,
      (__attribute__((address_space(3))) unsigned int*)l, 16, 0, 0);
}

// ---------------------------------------------------------------------------
// fp32 -> bf16 cast, 8 elems/thread
// ---------------------------------------------------------------------------
__global__ void cast_bf16(const float* __restrict__ src,
                          unsigned short* __restrict__ dst, int n8) {
  int i = blockIdx.x * blockDim.x + threadIdx.x;
  if (i >= n8) return;
  const float4* s4 = (const float4*)src;
  float4 a = s4[2 * (size_t)i], b = s4[2 * (size_t)i + 1];
  short8 o;
  o[0] = (short)f2bf(a.x); o[1] = (short)f2bf(a.y);
  o[2] = (short)f2bf(a.z); o[3] = (short)f2bf(a.w);
  o[4] = (short)f2bf(b.x); o[5] = (short)f2bf(b.y);
  o[6] = (short)f2bf(b.z); o[7] = (short)f2bf(b.w);
  *(short8*)(dst + 8 * (size_t)i) = o;
}

// ---------------------------------------------------------------------------
// C[M,N] = A[M,K] * B[N,K]^T   (both k-contiguous bf16), M=4096 N=2048 K=2048
// 128x128 tile, BK=32, 256 thr = 4 waves, each wave 64x64 via 4x4 16x16x32 MFMA.
// LDS chunk xor-swizzle (c ^ ((row>>2)&3)) -> frag ds_read_b128 2-way (free).
// ---------------------------------------------------------------------------
constexpr int GM = 4096, GN = 2048, GK = 2048;

template <bool STORE_BF16>
__global__ __launch_bounds__(256) void gemm_bt(
    const unsigned short* __restrict__ A, const unsigned short* __restrict__ B,
    void* __restrict__ Cout) {
  __shared__ short As[128 * 32];
  __shared__ short Bs[128 * 32];
  const int t = threadIdx.x;
  const int wave = t >> 6, lane = t & 63;
  const int row0 = blockIdx.x * 128, col0 = blockIdx.y * 128;
  const int wrow = (wave >> 1) * 64, wcol = (wave & 1) * 64;

  f32x4 acc[4][4] = {};

  // staging: instr ii in {0,1}: row = ii*64 + wave*16 + (lane>>2);
  // stored chunk pos = lane&3 holds global chunk cg = (lane&3)^(lane>>4)
  const int srow = wave * 16 + (lane >> 2);
  const int cg = (lane & 3) ^ (lane >> 4);
  const unsigned short* Ag0 = A + (size_t)(row0 + srow) * GK + cg * 8;
  const unsigned short* Ag1 = A + (size_t)(row0 + 64 + srow) * GK + cg * 8;
  const unsigned short* Bg0 = B + (size_t)(col0 + srow) * GK + cg * 8;
  const unsigned short* Bg1 = B + (size_t)(col0 + 64 + srow) * GK + cg * 8;
  char* lA0 = (char*)As + wave * 1024;
  char* lA1 = (char*)As + 4096 + wave * 1024;
  char* lB0 = (char*)Bs + wave * 1024;
  char* lB1 = (char*)Bs + 4096 + wave * 1024;

  const int quad = lane >> 4, l15 = lane & 15;
  const int cpos = quad ^ ((l15 >> 2) & 3);  // read-side swizzle
  const short* ap[4];
  const short* bp[4];
#pragma unroll
  for (int i = 0; i < 4; ++i) {
    ap[i] = As + (wrow + i * 16 + l15) * 32 + cpos * 8;
    bp[i] = Bs + (wcol + i * 16 + l15) * 32 + cpos * 8;
  }

  for (int kk = 0; kk < GK; kk += 32) {
    async16(Ag0 + kk, lA0);
    async16(Ag1 + kk, lA1);
    async16(Bg0 + kk, lB0);
    async16(Bg1 + kk, lB1);
    __syncthreads();  // vmcnt(0) drained here by compiler
    short8 af[4], bf[4];
#pragma unroll
    for (int i = 0; i < 4; ++i) af[i] = *(const short8*)ap[i];
#pragma unroll
    for (int i = 0; i < 4; ++i) bf[i] = *(const short8*)bp[i];
#pragma unroll
    for (int mi = 0; mi < 4; ++mi)
#pragma unroll
      for (int ni = 0; ni < 4; ++ni)
        acc[mi][ni] = __builtin_amdgcn_mfma_f32_16x16x32_bf16(
            af[mi], bf[ni], acc[mi][ni], 0, 0, 0);
    __syncthreads();
  }

  // C/D layout: row = quad*4 + reg, col = lane&15 (m89/m91-verified)
#pragma unroll
  for (int mi = 0; mi < 4; ++mi)
#pragma unroll
    for (int ni = 0; ni < 4; ++ni)
#pragma unroll
      for (int r = 0; r < 4; ++r) {
        int row = row0 + wrow + mi * 16 + quad * 4 + r;
        int col = col0 + wcol + ni * 16 + l15;
        if (STORE_BF16)
          ((unsigned short*)Cout)[(size_t)row * GN + col] = f2bf(acc[mi][ni][r]);
        else
          ((float*)Cout)[(size_t)row * GN + col] = acc[mi][ni][r];
      }
}

// ---------------------------------------------------------------------------
// Flash attention, fp32 compute from bf16 q/k/v, sliding-window causal.
// Block = 256 thr handles one (b, h, 64-query tile). K/V share one LDS buffer
// (V staged during softmax phase). Online softmax state duplicated per row
// across 4 threads. LDS chunk xor-swizzle (c ^ ((row>>2)&7)) for conflict-free
// K-fragment reads.
// ---------------------------------------------------------------------------
__global__ __launch_bounds__(256) void attn_kernel(
    const unsigned short* __restrict__ Qm, const unsigned short* __restrict__ Km,
    const unsigned short* __restrict__ Vm, unsigned short* __restrict__ Om,
    const int* __restrict__ amask, const int* __restrict__ winp) {
  constexpr int S = 2048, D = 2048, HD = 128;
  const float SCALE = 0.08838834764831845f;  // 1/sqrt(128)

  __shared__ short Qs[64 * 128];
  __shared__ short KV[64 * 128];
  __shared__ float Ss[64 * 68];  // stride 68 floats: pad for bank spread
  __shared__ float Al[64];

  const int t = threadIdx.x;
  const int wave = t >> 6, lane = t & 63;
  const int qt = blockIdx.x, h = blockIdx.y, b = blockIdx.z;
  const int qi0 = qt * 64;
  const int win = winp[0];

  const int st_r = lane >> 4;   // staging: row within wave's 4
  const int st_c = lane & 15;   // staging: stored chunk pos

  // stage Q tile once
#pragma unroll
  for (int ii = 0; ii < 4; ++ii) {
    int row = ii * 16 + wave * 4 + st_r;
    int cgq = st_c ^ ((row >> 2) & 7);
    async16(Qm + (size_t)(b * S + qi0 + row) * D + h * HD + cgq * 8,
            (char*)Qs + ii * 4096 + wave * 1024);
  }

  float m_old = -1e30f, l_old = 0.f;  // per row, dup over 4 threads (t&3)
  float o[4][8] = {};                 // PV accum: 4 rows x 8 d

  int lowj = qi0 - win + 1;
  if (lowj < 0) lowj = 0;
  const int jt0 = lowj >> 6;

  const int tr = t >> 4, tc = t & 15;  // QK / PV grids
  const int rb = tr * 4;
  const int sr = t >> 2, spart = t & 3;  // softmax grid

  for (int jt = jt0; jt <= qt; ++jt) {
    const int j0 = jt * 64;
    __syncthreads();  // (A) prev PV done with KV/Ss/Al
#pragma unroll
    for (int ii = 0; ii < 4; ++ii) {
      int row = ii * 16 + wave * 4 + st_r;
      int cgk = st_c ^ ((row >> 2) & 7);
      async16(Km + (size_t)(b * S + j0 + row) * D + h * HD + cgk * 8,
              (char*)KV + ii * 4096 + wave * 1024);
    }
    __syncthreads();  // (B) K visible

    // ---- QK^T: thread computes S[rb..rb+3][jb..jb+3] ----
    {
      const int jb = tc * 4;
      float acc[4][4] = {};
#pragma unroll
      for (int dc = 0; dc < 16; ++dc) {
        uint4 k8[4];
#pragma unroll
        for (int j = 0; j < 4; ++j)
          k8[j] = *(const uint4*)&KV[(jb + j) * 128 + (dc ^ (tc & 7)) * 8];
        float kf[4][8];
#pragma unroll
        for (int j = 0; j < 4; ++j) unpack8(k8[j], kf[j]);
#pragma unroll
        for (int i = 0; i < 4; ++i) {
          uint4 q8 = *(const uint4*)&Qs[(rb + i) * 128 + (dc ^ (tr & 7)) * 8];
          float qf[8];
          unpack8(q8, qf);
#pragma unroll
          for (int e = 0; e < 8; ++e)
#pragma unroll
            for (int j = 0; j < 4; ++j) acc[i][j] += qf[e] * kf[j][e];
        }
      }
      int amv[4];
#pragma unroll
      for (int j = 0; j < 4; ++j) amv[j] = amask[b * S + j0 + jb + j];
#pragma unroll
      for (int i = 0; i < 4; ++i) {
        int gi = qi0 + rb + i;
        float4 sv;
        float* svp = (float*)&sv;
#pragma unroll
        for (int j = 0; j < 4; ++j) {
          int gj = j0 + jb + j;
          bool ok = (gj <= gi) && (gj >= gi - win + 1) && (amv[j] != 0);
          svp[j] = ok ? acc[i][j] * SCALE : -1e30f;
        }
        *(float4*)&Ss[(rb + i) * 68 + jb] = sv;
      }
    }
    __syncthreads();  // (C) Ss ready; K fully consumed

    // stage V into KV (overlaps softmax; disjoint LDS)
#pragma unroll
    for (int ii = 0; ii < 4; ++ii) {
      int row = ii * 16 + wave * 4 + st_r;
      int cgv = st_c ^ ((row >> 2) & 7);
      async16(Vm + (size_t)(b * S + j0 + row) * D + h * HD + cgv * 8,
              (char*)KV + ii * 4096 + wave * 1024);
    }
    // ---- online softmax: thread owns row sr, cols [spart*16, +16) ----
    {
      float* srow_p = &Ss[sr * 68 + spart * 16];
      float xv[16];
      *(float4*)&xv[0] = *(const float4*)(srow_p + 0);
      *(float4*)&xv[4] = *(const float4*)(srow_p + 4);
      *(float4*)&xv[8] = *(const float4*)(srow_p + 8);
      *(float4*)&xv[12] = *(const float4*)(srow_p + 12);
      float mx = -1e30f;
#pragma unroll
      for (int e = 0; e < 16; ++e) mx = fmaxf(mx, xv[e]);
      mx = fmaxf(mx, __shfl_xor(mx, 1));
      mx = fmaxf(mx, __shfl_xor(mx, 2));
      float m_new = fmaxf(m_old, mx);
      float sum = 0.f;
#pragma unroll
      for (int e = 0; e < 16; ++e) {
        float p = (xv[e] > -1e29f) ? __expf(xv[e] - m_new) : 0.f;
        xv[e] = p;
        sum += p;
      }
      *(float4*)(srow_p + 0) = *(const float4*)&xv[0];
      *(float4*)(srow_p + 4) = *(const float4*)&xv[4];
      *(float4*)(srow_p + 8) = *(const float4*)&xv[8];
      *(float4*)(srow_p + 12) = *(const float4*)&xv[12];
      sum += __shfl_xor(sum, 1);
      sum += __shfl_xor(sum, 2);
      float alpha = __expf(m_old - m_new);  // fully-masked tiles: p=0, l unchanged
      l_old = l_old * alpha + sum;
      m_old = m_new;
      if (spart == 0) Al[sr] = alpha;
    }
    __syncthreads();  // (D) V visible, P + alpha ready

    // ---- PV: thread owns rows rb..rb+3, d-chunk tc (8 cols) ----
    {
      float av[4];
#pragma unroll
      for (int i = 0; i < 4; ++i) av[i] = Al[rb + i];
#pragma unroll
      for (int i = 0; i < 4; ++i)
#pragma unroll
        for (int e = 0; e < 8; ++e) o[i][e] *= av[i];
#pragma unroll
      for (int jc = 0; jc < 8; ++jc) {
        float p[4][8];
#pragma unroll
        for (int i = 0; i < 4; ++i) {
          *(float4*)&p[i][0] = *(const float4*)&Ss[(rb + i) * 68 + jc * 8];
          *(float4*)&p[i][4] = *(const float4*)&Ss[(rb + i) * 68 + jc * 8 + 4];
        }
#pragma unroll
        for (int jj = 0; jj < 8; ++jj) {
          int j = jc * 8 + jj;
          uint4 v8 = *(const uint4*)&KV[j * 128 + (tc ^ ((j >> 2) & 7)) * 8];
          float vf[8];
          unpack8(v8, vf);
#pragma unroll
          for (int i = 0; i < 4; ++i) {
            float pv = p[i][jj];
#pragma unroll
            for (int e = 0; e < 8; ++e) o[i][e] += pv * vf[e];
          }
        }
      }
    }
  }

  __syncthreads();
  if (spart == 0) Al[sr] = 1.f / l_old;  // reuse Al for 1/l
  __syncthreads();
#pragma unroll
  for (int i = 0; i < 4; ++i) {
    float inv = Al[rb + i];
    short8 ov;
#pragma unroll
    for (int e = 0; e < 8; ++e) ov[e] = (short)f2bf(o[i][e] * inv);
    *(short8*)(Om + (size_t)(b * S + qi0 + rb + i) * D + h * HD + tc * 8) = ov;
  }
}

// ---------------------------------------------------------------------------
extern "C" void kernel_launch(void* const* d_in, const int* in_sizes, int n_in,
                              void* d_out, int out_size, void* d_ws,
                              size_t ws_size, hipStream_t stream) {
  (void)in_sizes; (void)n_in; (void)out_size; (void)ws_size;
  const float* x  = (const float*)d_in[0];
  const float* Wq = (const float*)d_in[1];
  const float* Wk = (const float*)d_in[2];
  const float* Wv = (const float*)d_in[3];
  const float* Wo = (const float*)d_in[4];
  const int* am   = (const int*)d_in[5];
  const int* win  = (const int*)d_in[6];
  // d_in[7] sink_tokens: unused (sink mask == causal in the reference)

  char* ws = (char*)d_ws;  // needs >= 117,440,512 bytes
  unsigned short* xb  = (unsigned short*)(ws + 0);
  unsigned short* wqb = (unsigned short*)(ws + 16777216);
  unsigned short* wkb = (unsigned short*)(ws + 25165824);
  unsigned short* wvb = (unsigned short*)(ws + 33554432);
  unsigned short* wob = (unsigned short*)(ws + 41943040);
  unsigned short* qb  = (unsigned short*)(ws + 50331648);
  unsigned short* kb  = (unsigned short*)(ws + 67108864);
  unsigned short* vb  = (unsigned short*)(ws + 83886080);
  unsigned short* ab  = (unsigned short*)(ws + 100663296);

  cast_bf16<<<dim3(4096), dim3(256), 0, stream>>>(x, xb, 1048576);
  cast_bf16<<<dim3(2048), dim3(256), 0, stream>>>(Wq, wqb, 524288);
  cast_bf16<<<dim3(2048), dim3(256), 0, stream>>>(Wk, wkb, 524288);
  cast_bf16<<<dim3(2048), dim3(256), 0, stream>>>(Wv, wvb, 524288);
  cast_bf16<<<dim3(2048), dim3(256), 0, stream>>>(Wo, wob, 524288);

  gemm_bt<true><<<dim3(32, 16), dim3(256), 0, stream>>>(xb, wqb, qb);
  gemm_bt<true><<<dim3(32, 16), dim3(256), 0, stream>>>(xb, wkb, kb);
  gemm_bt<true><<<dim3(32, 16), dim3(256), 0, stream>>>(xb, wvb, vb);

  attn_kernel<<<dim3(32, 16, 2), dim3(256), 0, stream>>>(qb, kb, vb, ab, am, win);

  gemm_bt<false><<<dim3(32, 16), dim3(256), 0, stream>>>(ab, wob, d_out);
}

// Round 2
// 407.511 us; speedup vs baseline: 7.6596x; 7.6596x over previous
//
#include <hip/hip_runtime.h>
#include <stdint.h>

// ============================================================================
// R2: bf16 MFMA GEMMs (m97 structure) + MFMA flash attention (16x16x32 bf16)
// Shapes fixed: B=2, S=2048, D=2048, H=16, HD=128, window=512 (runtime-read).
// ws layout (bytes): vtb@0(16M, aliases dead xb) | xb@0 | wq@16M wk@24M wv@32M
//   wo@40M q@48M k@64M v@80M attn_out@96M  -> 112 MB total.
// ============================================================================

typedef __attribute__((ext_vector_type(8))) short short8;
typedef __attribute__((ext_vector_type(4))) float f32x4;

#define DEV static __device__ __forceinline__

DEV unsigned short f2bf(float f) {
  unsigned u = __builtin_bit_cast(unsigned, f);
  u += 0x7fffu + ((u >> 16) & 1u);  // RNE
  return (unsigned short)(u >> 16);
}

// async global->LDS, 16B/lane; LDS dest = wave-uniform base + lane*16
DEV void async16(const void* g, void* l) {
  __builtin_amdgcn_global_load_lds(
      (const __attribute__((address_space(1))) unsigned int*)g,
      (__attribute__((address_space(3))) unsigned int*)l, 16, 0, 0);
}

// ---------------------------------------------------------------------------
// fp32 -> bf16 cast, 8 elems/thread
// ---------------------------------------------------------------------------
__global__ void cast_bf16(const float* __restrict__ src,
                          unsigned short* __restrict__ dst, int n8) {
  int i = blockIdx.x * blockDim.x + threadIdx.x;
  if (i >= n8) return;
  const float4* s4 = (const float4*)src;
  float4 a = s4[2 * (size_t)i], b = s4[2 * (size_t)i + 1];
  short8 o;
  o[0] = (short)f2bf(a.x); o[1] = (short)f2bf(a.y);
  o[2] = (short)f2bf(a.z); o[3] = (short)f2bf(a.w);
  o[4] = (short)f2bf(b.x); o[5] = (short)f2bf(b.y);
  o[6] = (short)f2bf(b.z); o[7] = (short)f2bf(b.w);
  *(short8*)(dst + 8 * (size_t)i) = o;
}

// ---------------------------------------------------------------------------
// C[M,N] = A[M,K] * B[N,K]^T  (k-contiguous bf16), M=4096 N=2048 K=2048
// ---------------------------------------------------------------------------
constexpr int GM = 4096, GN = 2048, GK = 2048;

template <bool STORE_BF16>
__global__ __launch_bounds__(256) void gemm_bt(
    const unsigned short* __restrict__ A, const unsigned short* __restrict__ B,
    void* __restrict__ Cout) {
  __shared__ short As[128 * 32];
  __shared__ short Bs[128 * 32];
  const int t = threadIdx.x;
  const int wave = t >> 6, lane = t & 63;
  const int row0 = blockIdx.x * 128, col0 = blockIdx.y * 128;
  const int wrow = (wave >> 1) * 64, wcol = (wave & 1) * 64;

  f32x4 acc[4][4] = {};

  const int srow = wave * 16 + (lane >> 2);
  const int cg = (lane & 3) ^ (lane >> 4);
  const unsigned short* Ag0 = A + (size_t)(row0 + srow) * GK + cg * 8;
  const unsigned short* Ag1 = A + (size_t)(row0 + 64 + srow) * GK + cg * 8;
  const unsigned short* Bg0 = B + (size_t)(col0 + srow) * GK + cg * 8;
  const unsigned short* Bg1 = B + (size_t)(col0 + 64 + srow) * GK + cg * 8;
  char* lA0 = (char*)As + wave * 1024;
  char* lA1 = (char*)As + 4096 + wave * 1024;
  char* lB0 = (char*)Bs + wave * 1024;
  char* lB1 = (char*)Bs + 4096 + wave * 1024;

  const int quad = lane >> 4, l15 = lane & 15;
  const int cpos = quad ^ ((l15 >> 2) & 3);
  const short* ap[4];
  const short* bp[4];
#pragma unroll
  for (int i = 0; i < 4; ++i) {
    ap[i] = As + (wrow + i * 16 + l15) * 32 + cpos * 8;
    bp[i] = Bs + (wcol + i * 16 + l15) * 32 + cpos * 8;
  }

  for (int kk = 0; kk < GK; kk += 32) {
    async16(Ag0 + kk, lA0);
    async16(Ag1 + kk, lA1);
    async16(Bg0 + kk, lB0);
    async16(Bg1 + kk, lB1);
    __syncthreads();
    short8 af[4], bf[4];
#pragma unroll
    for (int i = 0; i < 4; ++i) af[i] = *(const short8*)ap[i];
#pragma unroll
    for (int i = 0; i < 4; ++i) bf[i] = *(const short8*)bp[i];
#pragma unroll
    for (int mi = 0; mi < 4; ++mi)
#pragma unroll
      for (int ni = 0; ni < 4; ++ni)
        acc[mi][ni] = __builtin_amdgcn_mfma_f32_16x16x32_bf16(
            af[mi], bf[ni], acc[mi][ni], 0, 0, 0);
    __syncthreads();
  }

#pragma unroll
  for (int mi = 0; mi < 4; ++mi)
#pragma unroll
    for (int ni = 0; ni < 4; ++ni)
#pragma unroll
      for (int r = 0; r < 4; ++r) {
        int row = row0 + wrow + mi * 16 + quad * 4 + r;
        int col = col0 + wcol + ni * 16 + l15;
        if (STORE_BF16)
          ((unsigned short*)Cout)[(size_t)row * GN + col] = f2bf(acc[mi][ni][r]);
        else
          ((float*)Cout)[(size_t)row * GN + col] = acc[mi][ni][r];
      }
}

// ---------------------------------------------------------------------------
// V transpose: vb[b*S+s][d] -> vtb[(b*H + d>>7)*128 + (d&127)][s]
// 64x64 tiles, grid (S/64, D/64, B)
// ---------------------------------------------------------------------------
__global__ __launch_bounds__(256) void transpose_v(
    const unsigned short* __restrict__ vb, unsigned short* __restrict__ vtb) {
  __shared__ unsigned short tile[64][72];  // +8 pad breaks bank conflicts
  const int s0 = blockIdx.x * 64, d0 = blockIdx.y * 64, b = blockIdx.z;
  const int tid = threadIdx.x;
  const int c8 = tid & 7;
#pragma unroll
  for (int i = 0; i < 2; ++i) {
    int row = i * 32 + (tid >> 3);  // s-row in tile
    uint4 v = *(const uint4*)(vb + (size_t)(b * 2048 + s0 + row) * 2048 + d0 + c8 * 8);
    *(uint4*)&tile[row][c8 * 8] = v;
  }
  __syncthreads();
#pragma unroll
  for (int i = 0; i < 2; ++i) {
    int dr = i * 32 + (tid >> 3);  // d-row in tile
    short8 sv;
#pragma unroll
    for (int j = 0; j < 8; ++j) sv[j] = (short)tile[c8 * 8 + j][dr];
    int d = d0 + dr;
    int h = d >> 7, hd = d & 127;
    *(short8*)(vtb + ((size_t)(b * 16 + h) * 128 + hd) * 2048 + s0 + c8 * 8) = sv;
  }
}

// ---------------------------------------------------------------------------
// MFMA flash attention. Block = (q-tile 64, h, b), 4 waves; wave owns 16 q rows.
// Q A-frags in regs; K tile + V^T tile staged via global_load_lds (swizzled);
// online softmax in C-layout regs; P -> per-wave LDS (A-layout) -> PV MFMA.
// ---------------------------------------------------------------------------
__global__ __launch_bounds__(256, 3) void attn_mfma(
    const unsigned short* __restrict__ Qm, const unsigned short* __restrict__ Km,
    const unsigned short* __restrict__ Vt, unsigned short* __restrict__ Om,
    const int* __restrict__ amask, const int* __restrict__ winp) {
  constexpr int S = 2048, D = 2048, HD = 128;
  const float SCALE = 0.08838834764831845f;  // 1/sqrt(128)

  __shared__ short Ks[64 * 128];   // K[key][d], chunk-swizzled (16 chunks/row)
  __shared__ short Vts[128 * 64];  // Vt[d][key], chunk-swizzled (8 chunks/row)
  __shared__ short Ps[4][16 * 64]; // per-wave P[q][key], swizzled (8 chunks/row)

  const int t = threadIdx.x, w = t >> 6, lane = t & 63;
  const int quad = lane >> 4, l15 = lane & 15;
  const int l7 = l15 & 7;
  const int qt = blockIdx.x, h = blockIdx.y, b = blockIdx.z;
  const int qi0 = qt * 64;
  const int win = winp[0];

  // Q A-frags: A[m=l15][k=quad*8+j], 4 k-chunks of 32
  short8 qf[4];
  {
    const unsigned short* qp =
        Qm + (size_t)(b * S + qi0 + w * 16 + l15) * D + h * HD + quad * 8;
#pragma unroll
    for (int kc = 0; kc < 4; ++kc) qf[kc] = *(const short8*)(qp + kc * 32);
  }

  f32x4 o[8] = {};              // O[q=quad*4+r][d=ni2*16+l15]
  float m_r[4], l_r[4];
#pragma unroll
  for (int r = 0; r < 4; ++r) { m_r[r] = -1e30f; l_r[r] = 0.f; }

  int lowj = qi0 - win + 1;
  if (lowj < 0) lowj = 0;
  const int jt0 = lowj >> 6;

  const int krow = lane >> 4, kpos = lane & 15;  // K staging
  const int vrow = lane >> 3, vpos = lane & 7;   // Vt staging

  for (int jt = jt0; jt <= qt; ++jt) {
    const int j0 = jt * 64;
    __syncthreads();  // (A) prev tile's LDS reads done
    // stage K tile: 4 rows/wave/instr
#pragma unroll
    for (int ii = 0; ii < 4; ++ii) {
      int row = ii * 16 + w * 4 + krow;
      int c = kpos ^ (row & 7);
      async16(Km + (size_t)(b * S + j0 + row) * D + h * HD + c * 8,
              (char*)Ks + (ii * 16 + w * 4) * 256);
    }
    // stage Vt tile: 8 rows/wave/instr
#pragma unroll
    for (int ii = 0; ii < 4; ++ii) {
      int row = ii * 32 + w * 8 + vrow;
      int c = vpos ^ (row & 7);
      async16(Vt + ((size_t)(b * 16 + h) * 128 + row) * S + j0 + c * 8,
              (char*)Vts + (ii * 32 + w * 8) * 128);
    }
    __syncthreads();  // (B) K, Vt visible (vmcnt(0) drained)

    // ---- QK^T: S[q=quad*4+r][key=ni*16+l15] ----
    f32x4 sS[4];
#pragma unroll
    for (int ni = 0; ni < 4; ++ni) {
      f32x4 acc = {0.f, 0.f, 0.f, 0.f};
#pragma unroll
      for (int kc = 0; kc < 4; ++kc) {
        int pos = (kc * 4 + quad) ^ l7;
        short8 bk = *(const short8*)&Ks[(ni * 16 + l15) * 128 + pos * 8];
        acc = __builtin_amdgcn_mfma_f32_16x16x32_bf16(qf[kc], bk, acc, 0, 0, 0);
      }
      sS[ni] = acc;
    }

    // ---- mask + online softmax (quad-local rows) ----
    float sv[4][4];
    int amv[4];
#pragma unroll
    for (int ni = 0; ni < 4; ++ni) amv[ni] = amask[b * S + j0 + ni * 16 + l15];
#pragma unroll
    for (int ni = 0; ni < 4; ++ni)
#pragma unroll
      for (int r = 0; r < 4; ++r) {
        int gi = qi0 + w * 16 + quad * 4 + r;
        int gj = j0 + ni * 16 + l15;
        bool ok = (gj <= gi) && (gj >= gi - win + 1) && (amv[ni] != 0);
        sv[ni][r] = ok ? sS[ni][r] * SCALE : -1e30f;
      }
    float alpha[4], mnew[4];
#pragma unroll
    for (int r = 0; r < 4; ++r) {
      float mx = fmaxf(fmaxf(sv[0][r], sv[1][r]), fmaxf(sv[2][r], sv[3][r]));
      mx = fmaxf(mx, __shfl_xor(mx, 1));
      mx = fmaxf(mx, __shfl_xor(mx, 2));
      mx = fmaxf(mx, __shfl_xor(mx, 4));
      mx = fmaxf(mx, __shfl_xor(mx, 8));
      float mn = fmaxf(m_r[r], mx);
      alpha[r] = __expf(m_r[r] - mn);
      m_r[r] = mn;
      mnew[r] = mn;
    }
    float rs[4] = {0.f, 0.f, 0.f, 0.f};
#pragma unroll
    for (int ni = 0; ni < 4; ++ni)
#pragma unroll
      for (int r = 0; r < 4; ++r) {
        float p = (sv[ni][r] > -1e29f) ? __expf(sv[ni][r] - mnew[r]) : 0.f;
        sv[ni][r] = p;
        rs[r] += p;
      }
#pragma unroll
    for (int r = 0; r < 4; ++r) {
      float s = rs[r];
      s += __shfl_xor(s, 1);
      s += __shfl_xor(s, 2);
      s += __shfl_xor(s, 4);
      s += __shfl_xor(s, 8);
      l_r[r] = l_r[r] * alpha[r] + s;
    }
    // write P (bf16) into this wave's A-layout tile
#pragma unroll
    for (int ni = 0; ni < 4; ++ni)
#pragma unroll
      for (int r = 0; r < 4; ++r) {
        int row = quad * 4 + r;
        int col = ni * 16 + l15;
        int pos = (col >> 3) ^ (row & 7);
        Ps[w][row * 64 + pos * 8 + (col & 7)] = (short)f2bf(sv[ni][r]);
      }
    // rescale O
#pragma unroll
    for (int ni2 = 0; ni2 < 8; ++ni2)
#pragma unroll
      for (int r = 0; r < 4; ++r) o[ni2][r] *= alpha[r];

    // same-wave LDS write->read: drain lgkm, no barrier needed
    __asm__ __volatile__("s_waitcnt lgkmcnt(0)" ::: "memory");

    // ---- PV: O[q][d] += P[q][key] * Vt[d][key]^T ----
    short8 aP[2];
#pragma unroll
    for (int kc2 = 0; kc2 < 2; ++kc2) {
      int pos = (kc2 * 4 + quad) ^ l7;
      aP[kc2] = *(const short8*)&Ps[w][l15 * 64 + pos * 8];
    }
#pragma unroll
    for (int ni2 = 0; ni2 < 8; ++ni2) {
#pragma unroll
      for (int kc2 = 0; kc2 < 2; ++kc2) {
        int pos = (kc2 * 4 + quad) ^ l7;
        short8 bv = *(const short8*)&Vts[(ni2 * 16 + l15) * 64 + pos * 8];
        o[ni2] = __builtin_amdgcn_mfma_f32_16x16x32_bf16(aP[kc2], bv, o[ni2], 0, 0, 0);
      }
    }
  }

  // epilogue: O / l
  float inv[4];
#pragma unroll
  for (int r = 0; r < 4; ++r) inv[r] = 1.f / l_r[r];
#pragma unroll
  for (int ni2 = 0; ni2 < 8; ++ni2)
#pragma unroll
    for (int r = 0; r < 4; ++r) {
      int row = qi0 + w * 16 + quad * 4 + r;
      Om[(size_t)(b * S + row) * D + h * HD + ni2 * 16 + l15] =
          f2bf(o[ni2][r] * inv[r]);
    }
}

// ---------------------------------------------------------------------------
extern "C" void kernel_launch(void* const* d_in, const int* in_sizes, int n_in,
                              void* d_out, int out_size, void* d_ws,
                              size_t ws_size, hipStream_t stream) {
  (void)in_sizes; (void)n_in; (void)out_size; (void)ws_size;
  const float* x  = (const float*)d_in[0];
  const float* Wq = (const float*)d_in[1];
  const float* Wk = (const float*)d_in[2];
  const float* Wv = (const float*)d_in[3];
  const float* Wo = (const float*)d_in[4];
  const int* am   = (const int*)d_in[5];
  const int* win  = (const int*)d_in[6];
  // d_in[7] sink_tokens: unused (sink mask == causal per reference)

  char* ws = (char*)d_ws;  // needs >= 112 MB (round-1 verified)
  unsigned short* xb  = (unsigned short*)(ws + 0);
  unsigned short* vtb = (unsigned short*)(ws + 0);  // aliases xb (dead by then)
  unsigned short* wqb = (unsigned short*)(ws + 16777216);
  unsigned short* wkb = (unsigned short*)(ws + 25165824);
  unsigned short* wvb = (unsigned short*)(ws + 33554432);
  unsigned short* wob = (unsigned short*)(ws + 41943040);
  unsigned short* qb  = (unsigned short*)(ws + 50331648);
  unsigned short* kb  = (unsigned short*)(ws + 67108864);
  unsigned short* vb  = (unsigned short*)(ws + 83886080);
  unsigned short* ab  = (unsigned short*)(ws + 100663296);

  cast_bf16<<<dim3(4096), dim3(256), 0, stream>>>(x, xb, 1048576);
  cast_bf16<<<dim3(2048), dim3(256), 0, stream>>>(Wq, wqb, 524288);
  cast_bf16<<<dim3(2048), dim3(256), 0, stream>>>(Wk, wkb, 524288);
  cast_bf16<<<dim3(2048), dim3(256), 0, stream>>>(Wv, wvb, 524288);
  cast_bf16<<<dim3(2048), dim3(256), 0, stream>>>(Wo, wob, 524288);

  gemm_bt<true><<<dim3(32, 16), dim3(256), 0, stream>>>(xb, wqb, qb);
  gemm_bt<true><<<dim3(32, 16), dim3(256), 0, stream>>>(xb, wkb, kb);
  gemm_bt<true><<<dim3(32, 16), dim3(256), 0, stream>>>(xb, wvb, vb);

  transpose_v<<<dim3(32, 32, 2), dim3(256), 0, stream>>>(vb, vtb);

  attn_mfma<<<dim3(32, 16, 2), dim3(256), 0, stream>>>(qb, kb, vtb, ab, am, win);

  gemm_bt<false><<<dim3(32, 16), dim3(256), 0, stream>>>(ab, wob, d_out);
}

// Round 3
// 378.643 us; speedup vs baseline: 8.2436x; 1.0762x over previous
//
#include <hip/hip_runtime.h>
#include <stdint.h>

// ============================================================================
// R3: fused QKV GEMM (N=6144, 1536 blocks) + 128-q-row MFMA flash attention.
// Shapes fixed: B=2, S=2048, D=2048, H=16, HD=128, window=512 (runtime-read).
// ws layout (bytes): xb@0 (16M, vtb aliases after QKV gemm) | wqkv@16M (25.2M)
//   wob@41.9M | qb@48M kb@64M vb@80M (16M apart = 8388608 elems) | ab@96M.
// ============================================================================

typedef __attribute__((ext_vector_type(8))) short short8;
typedef __attribute__((ext_vector_type(4))) float f32x4;

#define DEV static __device__ __forceinline__

DEV unsigned short f2bf(float f) {
  unsigned u = __builtin_bit_cast(unsigned, f);
  u += 0x7fffu + ((u >> 16) & 1u);  // RNE
  return (unsigned short)(u >> 16);
}

// async global->LDS, 16B/lane; LDS dest = wave-uniform base + lane*16
DEV void async16(const void* g, void* l) {
  __builtin_amdgcn_global_load_lds(
      (const __attribute__((address_space(1))) unsigned int*)g,
      (__attribute__((address_space(3))) unsigned int*)l, 16, 0, 0);
}

// ---------------------------------------------------------------------------
// fp32 -> bf16 cast, 8 elems/thread
// ---------------------------------------------------------------------------
__global__ void cast_bf16(const float* __restrict__ src,
                          unsigned short* __restrict__ dst, int n8) {
  int i = blockIdx.x * blockDim.x + threadIdx.x;
  if (i >= n8) return;
  const float4* s4 = (const float4*)src;
  float4 a = s4[2 * (size_t)i], b = s4[2 * (size_t)i + 1];
  short8 o;
  o[0] = (short)f2bf(a.x); o[1] = (short)f2bf(a.y);
  o[2] = (short)f2bf(a.z); o[3] = (short)f2bf(a.w);
  o[4] = (short)f2bf(b.x); o[5] = (short)f2bf(b.y);
  o[6] = (short)f2bf(b.z); o[7] = (short)f2bf(b.w);
  *(short8*)(dst + 8 * (size_t)i) = o;
}

// ---------------------------------------------------------------------------
// C = A[M,K] * B[NT,K]^T, k-contiguous bf16. M=4096, K=2048.
// grid.y*128 = global col; nb = col>>11 selects output buffer (stride
// obuf_stride elems); local col = col & 2047, row stride 2048.
// ---------------------------------------------------------------------------
constexpr int GK = 2048, GN = 2048;

template <bool STORE_BF16>
__global__ __launch_bounds__(256) void gemm_bt(
    const unsigned short* __restrict__ A, const unsigned short* __restrict__ B,
    void* __restrict__ Cout, size_t obuf_stride) {
  __shared__ short As[128 * 32];
  __shared__ short Bs[128 * 32];
  const int t = threadIdx.x;
  const int wave = t >> 6, lane = t & 63;
  const int row0 = blockIdx.x * 128;
  const int col0g = blockIdx.y * 128;            // global col in [0, N_total)
  const int nb = col0g >> 11, col0 = col0g & 2047;
  const int wrow = (wave >> 1) * 64, wcol = (wave & 1) * 64;

  f32x4 acc[4][4] = {};

  const int srow = wave * 16 + (lane >> 2);
  const int cg = (lane & 3) ^ (lane >> 4);
  const unsigned short* Ag0 = A + (size_t)(row0 + srow) * GK + cg * 8;
  const unsigned short* Ag1 = A + (size_t)(row0 + 64 + srow) * GK + cg * 8;
  const unsigned short* Bg0 = B + (size_t)(col0g + srow) * GK + cg * 8;
  const unsigned short* Bg1 = B + (size_t)(col0g + 64 + srow) * GK + cg * 8;
  char* lA0 = (char*)As + wave * 1024;
  char* lA1 = (char*)As + 4096 + wave * 1024;
  char* lB0 = (char*)Bs + wave * 1024;
  char* lB1 = (char*)Bs + 4096 + wave * 1024;

  const int quad = lane >> 4, l15 = lane & 15;
  const int cpos = quad ^ ((l15 >> 2) & 3);
  const short* ap[4];
  const short* bp[4];
#pragma unroll
  for (int i = 0; i < 4; ++i) {
    ap[i] = As + (wrow + i * 16 + l15) * 32 + cpos * 8;
    bp[i] = Bs + (wcol + i * 16 + l15) * 32 + cpos * 8;
  }

  for (int kk = 0; kk < GK; kk += 32) {
    async16(Ag0 + kk, lA0);
    async16(Ag1 + kk, lA1);
    async16(Bg0 + kk, lB0);
    async16(Bg1 + kk, lB1);
    __syncthreads();
    short8 af[4], bf[4];
#pragma unroll
    for (int i = 0; i < 4; ++i) af[i] = *(const short8*)ap[i];
#pragma unroll
    for (int i = 0; i < 4; ++i) bf[i] = *(const short8*)bp[i];
#pragma unroll
    for (int mi = 0; mi < 4; ++mi)
#pragma unroll
      for (int ni = 0; ni < 4; ++ni)
        acc[mi][ni] = __builtin_amdgcn_mfma_f32_16x16x32_bf16(
            af[mi], bf[ni], acc[mi][ni], 0, 0, 0);
    __syncthreads();
  }

#pragma unroll
  for (int mi = 0; mi < 4; ++mi)
#pragma unroll
    for (int ni = 0; ni < 4; ++ni)
#pragma unroll
      for (int r = 0; r < 4; ++r) {
        int row = row0 + wrow + mi * 16 + quad * 4 + r;
        int col = col0 + wcol + ni * 16 + l15;
        if (STORE_BF16)
          ((unsigned short*)Cout)[nb * obuf_stride + (size_t)row * GN + col] =
              f2bf(acc[mi][ni][r]);
        else
          ((float*)Cout)[nb * obuf_stride + (size_t)row * GN + col] =
              acc[mi][ni][r];
      }
}

// ---------------------------------------------------------------------------
// V transpose: vb[b*S+s][d] -> vtb[(b*H + d>>7)*128 + (d&127)][s]
// ---------------------------------------------------------------------------
__global__ __launch_bounds__(256) void transpose_v(
    const unsigned short* __restrict__ vb, unsigned short* __restrict__ vtb) {
  __shared__ unsigned short tile[64][72];
  const int s0 = blockIdx.x * 64, d0 = blockIdx.y * 64, b = blockIdx.z;
  const int tid = threadIdx.x;
  const int c8 = tid & 7;
#pragma unroll
  for (int i = 0; i < 2; ++i) {
    int row = i * 32 + (tid >> 3);
    uint4 v = *(const uint4*)(vb + (size_t)(b * 2048 + s0 + row) * 2048 + d0 + c8 * 8);
    *(uint4*)&tile[row][c8 * 8] = v;
  }
  __syncthreads();
#pragma unroll
  for (int i = 0; i < 2; ++i) {
    int dr = i * 32 + (tid >> 3);
    short8 sv;
#pragma unroll
    for (int j = 0; j < 8; ++j) sv[j] = (short)tile[c8 * 8 + j][dr];
    int d = d0 + dr;
    int h = d >> 7, hd = d & 127;
    *(short8*)(vtb + ((size_t)(b * 16 + h) * 128 + hd) * 2048 + s0 + c8 * 8) = sv;
  }
}

// ---------------------------------------------------------------------------
// MFMA flash attention, 128 q-rows per block. Block = (q-tile, h, b), 4 waves;
// wave owns 32 q rows (2 m-subtiles). K + V^T staged via global_load_lds
// (swizzled, 2-way free); softmax in C-layout regs; P -> per-wave LDS
// (A-layout, no barrier) -> PV MFMA. Wave-level skip of out-of-window tiles.
// ---------------------------------------------------------------------------
__global__ __launch_bounds__(256, 2) void attn_mfma(
    const unsigned short* __restrict__ Qm, const unsigned short* __restrict__ Km,
    const unsigned short* __restrict__ Vt, unsigned short* __restrict__ Om,
    const int* __restrict__ amask, const int* __restrict__ winp) {
  constexpr int S = 2048, D = 2048, HD = 128;
  const float SCALE = 0.08838834764831845f;  // 1/sqrt(128)

  __shared__ short Ks[64 * 128];       // K[key][d], swizzled 16 chunks/row
  __shared__ short Vts[128 * 64];      // Vt[d][key], swizzled 8 chunks/row
  __shared__ short Ps[4][2][16 * 64];  // per-wave, per-mi P[q][key]

  const int t = threadIdx.x, w = t >> 6, lane = t & 63;
  const int quad = lane >> 4, l15 = lane & 15;
  const int l7 = l15 & 7;
  const int qt = blockIdx.x, h = blockIdx.y, b = blockIdx.z;
  const int qi0 = qt * 128;
  const int win = winp[0];

  // Q A-frags for the wave's 2 m-subtiles: A[m=l15][k=quad*8+j]
  short8 qf[2][4];
#pragma unroll
  for (int mi = 0; mi < 2; ++mi) {
    const unsigned short* qp =
        Qm + (size_t)(b * S + qi0 + w * 32 + mi * 16 + l15) * D + h * HD + quad * 8;
#pragma unroll
    for (int kc = 0; kc < 4; ++kc) qf[mi][kc] = *(const short8*)(qp + kc * 32);
  }

  f32x4 o[2][8] = {};  // O[mi][d=ni2*16+l15], rows quad*4+r
  float m_r[2][4], l_r[2][4];
#pragma unroll
  for (int mi = 0; mi < 2; ++mi)
#pragma unroll
    for (int r = 0; r < 4; ++r) { m_r[mi][r] = -1e30f; l_r[mi][r] = 0.f; }

  int lowj = qi0 - win + 1;
  if (lowj < 0) lowj = 0;
  const int jt0 = lowj >> 6, jt1 = 2 * qt + 1;

  const int gmin = qi0 + w * 32, gmax = gmin + 31;  // wave's q-row range
  const int krow = lane >> 4, kpos = lane & 15;     // K staging
  const int vrow = lane >> 3, vpos = lane & 7;      // Vt staging

  for (int jt = jt0; jt <= jt1; ++jt) {
    const int j0 = jt * 64;
    __syncthreads();  // (A) prev tile's LDS reads done
#pragma unroll
    for (int ii = 0; ii < 4; ++ii) {
      int row = ii * 16 + w * 4 + krow;
      int c = kpos ^ (row & 7);
      async16(Km + (size_t)(b * S + j0 + row) * D + h * HD + c * 8,
              (char*)Ks + (ii * 16 + w * 4) * 256);
    }
#pragma unroll
    for (int ii = 0; ii < 4; ++ii) {
      int row = ii * 32 + w * 8 + vrow;
      int c = vpos ^ (row & 7);
      async16(Vt + ((size_t)(b * 16 + h) * 128 + row) * S + j0 + c * 8,
              (char*)Vts + (ii * 32 + w * 8) * 128);
    }
    __syncthreads();  // (B) K, Vt visible

    // wave-uniform skip: no (q,k) pair of this wave in-window for this tile
    if (j0 > gmax || j0 + 63 < gmin - win + 1) continue;

    int amv[4];
#pragma unroll
    for (int ni = 0; ni < 4; ++ni) amv[ni] = amask[b * S + j0 + ni * 16 + l15];

    // ---- QK^T for both m-subtiles (B-frags shared) ----
    f32x4 sS[2][4];
#pragma unroll
    for (int ni = 0; ni < 4; ++ni) {
      f32x4 a0 = {0.f, 0.f, 0.f, 0.f}, a1 = {0.f, 0.f, 0.f, 0.f};
#pragma unroll
      for (int kc = 0; kc < 4; ++kc) {
        int pos = (kc * 4 + quad) ^ l7;
        short8 bk = *(const short8*)&Ks[(ni * 16 + l15) * 128 + pos * 8];
        a0 = __builtin_amdgcn_mfma_f32_16x16x32_bf16(qf[0][kc], bk, a0, 0, 0, 0);
        a1 = __builtin_amdgcn_mfma_f32_16x16x32_bf16(qf[1][kc], bk, a1, 0, 0, 0);
      }
      sS[0][ni] = a0;
      sS[1][ni] = a1;
    }

    // ---- mask + online softmax + P write, per m-subtile ----
    float alpha[2][4];
#pragma unroll
    for (int mi = 0; mi < 2; ++mi) {
      float sv[4][4];
#pragma unroll
      for (int ni = 0; ni < 4; ++ni)
#pragma unroll
        for (int r = 0; r < 4; ++r) {
          int gi = qi0 + w * 32 + mi * 16 + quad * 4 + r;
          int gj = j0 + ni * 16 + l15;
          bool ok = (gj <= gi) && (gj >= gi - win + 1) && (amv[ni] != 0);
          sv[ni][r] = ok ? sS[mi][ni][r] * SCALE : -1e30f;
        }
      float mnew[4];
#pragma unroll
      for (int r = 0; r < 4; ++r) {
        float mx = fmaxf(fmaxf(sv[0][r], sv[1][r]), fmaxf(sv[2][r], sv[3][r]));
        mx = fmaxf(mx, __shfl_xor(mx, 1));
        mx = fmaxf(mx, __shfl_xor(mx, 2));
        mx = fmaxf(mx, __shfl_xor(mx, 4));
        mx = fmaxf(mx, __shfl_xor(mx, 8));
        float mn = fmaxf(m_r[mi][r], mx);
        alpha[mi][r] = __expf(m_r[mi][r] - mn);
        m_r[mi][r] = mn;
        mnew[r] = mn;
      }
      float rs[4] = {0.f, 0.f, 0.f, 0.f};
#pragma unroll
      for (int ni = 0; ni < 4; ++ni)
#pragma unroll
        for (int r = 0; r < 4; ++r) {
          float p = (sv[ni][r] > -1e29f) ? __expf(sv[ni][r] - mnew[r]) : 0.f;
          sv[ni][r] = p;
          rs[r] += p;
        }
#pragma unroll
      for (int r = 0; r < 4; ++r) {
        float s = rs[r];
        s += __shfl_xor(s, 1);
        s += __shfl_xor(s, 2);
        s += __shfl_xor(s, 4);
        s += __shfl_xor(s, 8);
        l_r[mi][r] = l_r[mi][r] * alpha[mi][r] + s;
      }
#pragma unroll
      for (int ni = 0; ni < 4; ++ni)
#pragma unroll
        for (int r = 0; r < 4; ++r) {
          int row = quad * 4 + r;
          int col = ni * 16 + l15;
          int pos = (col >> 3) ^ (row & 7);
          Ps[w][mi][row * 64 + pos * 8 + (col & 7)] = (short)f2bf(sv[ni][r]);
        }
    }
    // rescale O
#pragma unroll
    for (int mi = 0; mi < 2; ++mi)
#pragma unroll
      for (int ni2 = 0; ni2 < 8; ++ni2)
#pragma unroll
        for (int r = 0; r < 4; ++r) o[mi][ni2][r] *= alpha[mi][r];

    // same-wave LDS write->read: drain lgkm, no barrier needed
    __asm__ __volatile__("s_waitcnt lgkmcnt(0)" ::: "memory");

    // ---- PV: O[mi] += P[mi] * Vt^T (B-frags shared across mi) ----
    short8 aP[2][2];
#pragma unroll
    for (int mi = 0; mi < 2; ++mi)
#pragma unroll
      for (int kc2 = 0; kc2 < 2; ++kc2) {
        int pos = (kc2 * 4 + quad) ^ l7;
        aP[mi][kc2] = *(const short8*)&Ps[w][mi][l15 * 64 + pos * 8];
      }
#pragma unroll
    for (int ni2 = 0; ni2 < 8; ++ni2)
#pragma unroll
      for (int kc2 = 0; kc2 < 2; ++kc2) {
        int pos = (kc2 * 4 + quad) ^ l7;
        short8 bv = *(const short8*)&Vts[(ni2 * 16 + l15) * 64 + pos * 8];
        o[0][ni2] = __builtin_amdgcn_mfma_f32_16x16x32_bf16(aP[0][kc2], bv,
                                                            o[0][ni2], 0, 0, 0);
        o[1][ni2] = __builtin_amdgcn_mfma_f32_16x16x32_bf16(aP[1][kc2], bv,
                                                            o[1][ni2], 0, 0, 0);
      }
  }

  // epilogue: O / l
#pragma unroll
  for (int mi = 0; mi < 2; ++mi) {
    float inv[4];
#pragma unroll
    for (int r = 0; r < 4; ++r) inv[r] = 1.f / l_r[mi][r];
#pragma unroll
    for (int ni2 = 0; ni2 < 8; ++ni2)
#pragma unroll
      for (int r = 0; r < 4; ++r) {
        int row = qi0 + w * 32 + mi * 16 + quad * 4 + r;
        Om[(size_t)(b * S + row) * D + h * HD + ni2 * 16 + l15] =
            f2bf(o[mi][ni2][r] * inv[r]);
      }
  }
}

// ---------------------------------------------------------------------------
extern "C" void kernel_launch(void* const* d_in, const int* in_sizes, int n_in,
                              void* d_out, int out_size, void* d_ws,
                              size_t ws_size, hipStream_t stream) {
  (void)in_sizes; (void)n_in; (void)out_size; (void)ws_size;
  const float* x  = (const float*)d_in[0];
  const float* Wq = (const float*)d_in[1];
  const float* Wk = (const float*)d_in[2];
  const float* Wv = (const float*)d_in[3];
  const float* Wo = (const float*)d_in[4];
  const int* am   = (const int*)d_in[5];
  const int* win  = (const int*)d_in[6];
  // d_in[7] sink_tokens: unused (sink mask == causal per reference)

  char* ws = (char*)d_ws;  // needs >= 112 MB
  unsigned short* xb   = (unsigned short*)(ws + 0);
  unsigned short* vtb  = (unsigned short*)(ws + 0);  // aliases xb (dead then)
  unsigned short* wqkv = (unsigned short*)(ws + 16777216);  // [6144,2048]
  unsigned short* wob  = (unsigned short*)(ws + 41943040);
  unsigned short* qb   = (unsigned short*)(ws + 50331648);
  unsigned short* kb   = (unsigned short*)(ws + 67108864);  // qb + 8388608
  unsigned short* vb   = (unsigned short*)(ws + 83886080);  // qb + 2*8388608
  unsigned short* ab   = (unsigned short*)(ws + 100663296);

  cast_bf16<<<dim3(4096), dim3(256), 0, stream>>>(x, xb, 1048576);
  cast_bf16<<<dim3(2048), dim3(256), 0, stream>>>(Wq, wqkv, 524288);
  cast_bf16<<<dim3(2048), dim3(256), 0, stream>>>(Wk, wqkv + 4194304, 524288);
  cast_bf16<<<dim3(2048), dim3(256), 0, stream>>>(Wv, wqkv + 8388608, 524288);
  cast_bf16<<<dim3(2048), dim3(256), 0, stream>>>(Wo, wob, 524288);

  // fused QKV: N_total = 6144; col block >>11 -> {qb, kb, vb}
  gemm_bt<true><<<dim3(32, 48), dim3(256), 0, stream>>>(xb, wqkv, qb, 8388608);

  transpose_v<<<dim3(32, 32, 2), dim3(256), 0, stream>>>(vb, vtb);

  attn_mfma<<<dim3(16, 16, 2), dim3(256), 0, stream>>>(qb, kb, vtb, ab, am, win);

  gemm_bt<false><<<dim3(32, 16), dim3(256), 0, stream>>>(ab, wob, d_out, 0);
}